// Round 6
// baseline (261.560 us; speedup 1.0000x reference)
//
#include <hip/hip_runtime.h>
#include <stdint.h>
#include <math.h>

// BSRBF-KAN layer, FUSED, single-BB interleaved pipeline (round 6):
// out = relu(LN(x)) @ base_W^T + (bspline+rbf)(LN(x)) @ spline_W^T
// K = 512 (relu region, A0 via global_load_lds) + 4096 (basis, computed into LDS).
// Round-6 theory: rounds 2-5 all showed MfmaUtil+VALUBusy+LDS summing to
// ~100% serially.  Cause: s_setprio + sched_barrier(0) around the MFMA
// cluster act as scheduling fences -> each wave executes [reads][basis][MFMA]
// as disjoint blocks; 2 lockstep waves/SIMD saturate one pipe at a time.
// Fix: ONE branch-free BB per steady K-tile with NO fences except the
// tile-boundary waitcnt+barrier; LLVM machine scheduler interleaves basis
// VALU / GLL / MFMA (MFMA doesn't block its wave; VALU issues under it).
// LDS is chunk-major [chunk][row][16B] (r5-verified, 0 conflicts): all
// offsets compile-time; basis xn = one dword load (2 evals/thread).
// Tile: BM=128 x BN=256, BK=64, 8 waves, 96.2 KB LDS, grid=256 (1 block/CU).
//   ws: [W: 512*4608 f16][XN: 16384*512 f16][A0: 16384*512 f16]

#define D_IN  512
#define D_OUT 512
#define NB    8
#define KTOT  (D_IN + D_IN * NB)   // 4608
#define ROWS  16384
#define NT    (KTOT / 64)          // 72

typedef __attribute__((ext_vector_type(2))) _Float16 f16x2;
typedef __attribute__((ext_vector_type(8))) _Float16 f16x8;
typedef __attribute__((ext_vector_type(4))) float f32x4;

__device__ __forceinline__ float h2f(unsigned short u) {
  return (float)__builtin_bit_cast(_Float16, u);
}
__device__ __forceinline__ short f2h(float f) {
  return (short)__builtin_bit_cast(unsigned short, (_Float16)f);  // RNE
}
__device__ __forceinline__ unsigned pkrtz_u(float a, float b) {
  return __builtin_bit_cast(unsigned, __builtin_amdgcn_cvt_pkrtz(a, b));
}
__device__ __forceinline__ unsigned pkadd_f16(unsigned a, unsigned b) {
  f16x2 x = __builtin_bit_cast(f16x2, a), y = __builtin_bit_cast(f16x2, b);
  f16x2 r = x + y;
  return __builtin_bit_cast(unsigned, r);
}

// ---------------- prep: weight interleave + LayerNorm, one launch --------
__global__ __launch_bounds__(256) void prep_kernel(
    const float* __restrict__ x, const float* __restrict__ gamma,
    const float* __restrict__ beta, const float* __restrict__ bw,
    const float* __restrict__ sw, short* __restrict__ XN,
    short* __restrict__ A0, short* __restrict__ W) {
  if (blockIdx.x >= ROWS / 4) {
    const int o = blockIdx.x - ROWS / 4;
    for (int k = threadIdx.x; k < KTOT; k += 256) {
      const float v = (k < D_IN) ? bw[o * D_IN + k]
                                 : sw[(size_t)o * (D_IN * NB) + (k - D_IN)];
      W[(size_t)o * KTOT + k] = f2h(v);
    }
    return;
  }
  const int tid = threadIdx.x;
  const int lane = tid & 63, wave = tid >> 6;
  const int row = blockIdx.x * 4 + wave;
  const float* xr = x + (size_t)row * D_IN + lane * 8;

  const float4 a = *(const float4*)(xr);
  const float4 b = *(const float4*)(xr + 4);
  float xv[8] = {a.x, a.y, a.z, a.w, b.x, b.y, b.z, b.w};
  float s = 0.0f, ss = 0.0f;
#pragma unroll
  for (int e = 0; e < 8; e++) { s += xv[e]; ss += xv[e] * xv[e]; }
#pragma unroll
  for (int off = 32; off > 0; off >>= 1) {
    s += __shfl_xor(s, off);
    ss += __shfl_xor(ss, off);
  }
  const float mu = s * (1.0f / D_IN);
  const float var = ss * (1.0f / D_IN) - mu * mu;
  const float rstd = 1.0f / sqrtf(var + 1e-5f);

  const float4 g0 = *(const float4*)(gamma + lane * 8);
  const float4 g1 = *(const float4*)(gamma + lane * 8 + 4);
  const float4 b0 = *(const float4*)(beta + lane * 8);
  const float4 b1 = *(const float4*)(beta + lane * 8 + 4);
  float gv[8] = {g0.x, g0.y, g0.z, g0.w, g1.x, g1.y, g1.z, g1.w};
  float bv[8] = {b0.x, b0.y, b0.z, b0.w, b1.x, b1.y, b1.z, b1.w};

  unsigned xp[4], rp[4];
#pragma unroll
  for (int h = 0; h < 4; h++) {
    const float n0 = (xv[2 * h] - mu) * rstd * gv[2 * h] + bv[2 * h];
    const float n1 = (xv[2 * h + 1] - mu) * rstd * gv[2 * h + 1] + bv[2 * h + 1];
    const unsigned h0 = (unsigned)(unsigned short)f2h(n0);
    const unsigned h1 = (unsigned)(unsigned short)f2h(n1);
    xp[h] = h0 | (h1 << 16);
    rp[h] = (unsigned)(unsigned short)f2h(fmaxf(n0, 0.0f)) |
            ((unsigned)(unsigned short)f2h(fmaxf(n1, 0.0f)) << 16);
  }
  const uint4 xq = {xp[0], xp[1], xp[2], xp[3]};
  const uint4 rq = {rp[0], rp[1], rp[2], rp[3]};
  *(uint4*)&XN[(size_t)row * D_IN + lane * 8] = xq;
  *(uint4*)&A0[(size_t)row * D_IN + lane * 8] = rq;
}

// ---------------- basis eval: one d -> 8 packed f16 (spline + rbf) -------
// (verified rounds 3-5) Spline via 14-entry perm-selector LUT; RBF via
// 3-transcendental cascade, z clamped to [-8,16].
__device__ __forceinline__ void basis_write(float xn, const uint4* lut,
                                            short* dst) {
  const float u = fmaf(xn, 1.66666667f, 5.5f);  // (xn+3.3)/0.6
  const float cf = floorf(u);
  const int c = (int)cf;
  const float t = u - cf;
  const float t2 = t * t, t3 = t2 * t, omt = 1.0f - t;
  const float v0 = t3 * 0.16666667f;
  const float v1 = fmaf(fmaf(fmaf(t, -0.5f, 0.5f), t, 0.5f), t, 0.16666667f);
  const float v2 = fmaf(t3, 0.5f, fmaf(t2, -1.0f, 0.66666667f));
  const float v3 = omt * omt * (omt * 0.16666667f);
  const unsigned va = pkrtz_u(v0, v1);
  const unsigned vb = pkrtz_u(v2, v3);

  float z = fmaf(xn, 2.80261895f, 4.20392842f);
  z = fminf(fmaxf(z, -8.0f), 16.0f);
  const float d3 = z - 3.60336723f;              // 3*DLT
  const float R3 = __builtin_amdgcn_exp2f(-(d3 * d3));
  const float G  = __builtin_amdgcn_exp2f(z * 2.40224482f);  // 2*DLT
  const float Gi = __builtin_amdgcn_rcpf(G);
  const float R4 = R3 * (G * 9.11881966e-4f);    // e^-7
  const float R5 = R4 * (G * 1.23409804e-4f);    // e^-9
  const float R6 = R5 * (G * 1.67017007e-5f);    // e^-11
  const float R7 = R6 * (G * 2.26032941e-6f);    // e^-13
  const float R2 = R3 * (Gi * 148.413159f);      // e^5
  const float R1 = R2 * (Gi * 20.0855369f);      // e^3
  const float R0 = R1 * (Gi * 2.71828183f);      // e^1

  const int idx = (c < -1 ? -1 : (c > 12 ? 12 : c)) + 1;
  const uint4 sel = lut[idx];
  const unsigned w0 = pkadd_f16(__builtin_amdgcn_perm(vb, va, sel.x), pkrtz_u(R0, R1));
  const unsigned w1 = pkadd_f16(__builtin_amdgcn_perm(vb, va, sel.y), pkrtz_u(R2, R3));
  const unsigned w2 = pkadd_f16(__builtin_amdgcn_perm(vb, va, sel.z), pkrtz_u(R4, R5));
  const unsigned w3 = pkadd_f16(__builtin_amdgcn_perm(vb, va, sel.w), pkrtz_u(R6, R7));
  const uint4 v4 = {w0, w1, w2, w3};
  *(uint4*)dst = v4;  // ds_write_b128
}

// ---------------- fused f16 MFMA GEMM, single-BB steady loop -------------
#define GLL(g, l)                                               \
  __builtin_amdgcn_global_load_lds(                             \
      (const __attribute__((address_space(1))) void*)(g),       \
      (__attribute__((address_space(3))) void*)(l), 16, 0, 0)

__global__ __launch_bounds__(512, 2) void gemm_kernel(
    const short* __restrict__ A0, const short* __restrict__ XN,
    const short* __restrict__ W, float* __restrict__ out) {
  // chunk-major: A buf [8 ch][128 row][8 sh] = 16 KB; B buf [8 ch][256 row][8 sh] = 32 KB
  __shared__ short As[2 * 8192];   // 32 KB double-buffered A
  __shared__ short Bs[2 * 16384];  // 64 KB double-buffered B
  __shared__ uint4 LUT[14];
  const int tid = threadIdx.x;                 // 512
  const int lane = tid & 63, wave = tid >> 6;  // 8 waves

  if (tid < 14) {  // perm-selector LUT: entry idx = c+1, c clamped [-1,12]
    const int cc = tid - 1;
    unsigned e[4];
#pragma unroll
    for (int h = 0; h < 4; ++h) {
      const int m = cc - 2 * h, m2 = m - 1;
      const unsigned lo =
          (m >= 0 && m <= 3) ? (unsigned)((2 * m) | ((2 * m + 1) << 8)) : 0x0C0Cu;
      const unsigned hi =
          (m2 >= 0 && m2 <= 3) ? (unsigned)((2 * m2) | ((2 * m2 + 1) << 8)) : 0x0C0Cu;
      e[h] = lo | (hi << 16);
    }
    const uint4 ev = {e[0], e[1], e[2], e[3]};
    LUT[tid] = ev;
  }

  const int f = blockIdx.x;          // pair 2g,2g+1 shares one A m-tile
  const int m0 = (f >> 1) * 128;
  const int n0 = (f & 1) * 256;
  const int wm = wave & 1, wn = wave >> 1;  // per-wave 64x64 output

  const f32x4 zero = {0.0f, 0.0f, 0.0f, 0.0f};
  f32x4 acc[4][4];
#pragma unroll
  for (int i = 0; i < 4; i++)
#pragma unroll
    for (int j = 0; j < 4; j++) acc[i][j] = zero;

  // GLL staging (chunk-major, dest = linear tid*16B within 8KB call region):
  //   A call j (j=0,1): ch = (tid>>7)+4j, row = tid&127
  //   B call j (j=0..3): ch = (tid>>8)+2j, row = tid&255
  const short* pA0 = A0 + (size_t)(m0 + (tid & 127)) * D_IN + (tid >> 7) * 8;
  const short* pB0 = W + (size_t)(n0 + (tid & 255)) * KTOT + (tid >> 8) * 8;

  // basis mapping: thread -> row = tid&127, chunks 2*(tid>>7)+{0,1};
  // xn for both = one dword at XN[m0+row][d0 + 2*(tid>>7)]
  const unsigned short* gX =
      (const unsigned short*)XN + (size_t)(m0 + (tid & 127)) * D_IN + (tid >> 7) * 2;
  const int bas0 = (tid >> 7) * 2048 + (tid & 127) * 8;  // shorts; +1024 for 2nd

  const int lr = lane & 15;
  const int q = lane >> 4;
  const int aofs = q * 1024 + (wm * 64 + lr) * 8;  // + kk2*4096 + mi*128
  const int bofs = q * 2048 + (wn * 64 + lr) * 8;  // + kk2*8192 + nj*128

  short* Acur = As;        short* Anxt = As + 8192;
  short* Bcur = Bs;        short* Bnxt = Bs + 16384;

  f16x8 af[2][4], bf[2][4];
#define READ_FRAGS(bufA, bufB)                                                 \
  do {                                                                         \
    _Pragma("unroll")                                                          \
    for (int kk2 = 0; kk2 < 2; kk2++) {                                        \
      _Pragma("unroll")                                                        \
      for (int mi = 0; mi < 4; mi++)                                           \
        af[kk2][mi] = *(const f16x8*)&(bufA)[aofs + kk2 * 4096 + mi * 128];    \
      _Pragma("unroll")                                                        \
      for (int nj = 0; nj < 4; nj++)                                           \
        bf[kk2][nj] = *(const f16x8*)&(bufB)[bofs + kk2 * 8192 + nj * 128];    \
    }                                                                          \
  } while (0)

#define MFMA_ALL()                                                             \
  do {                                                                         \
    _Pragma("unroll")                                                          \
    for (int kk2 = 0; kk2 < 2; kk2++)                                          \
      _Pragma("unroll")                                                        \
      for (int mi = 0; mi < 4; mi++)                                           \
        _Pragma("unroll")                                                      \
        for (int nj = 0; nj < 4; nj++)                                         \
          acc[mi][nj] = __builtin_amdgcn_mfma_f32_16x16x32_f16(                \
              af[kk2][mi], bf[kk2][nj], acc[mi][nj], 0, 0, 0);                 \
  } while (0)

  // prologue: stage tile 0
#pragma unroll
  for (int j = 0; j < 2; j++) GLL(pA0 + j * 32, Acur + j * 4096 + wave * 512);
#pragma unroll
  for (int j = 0; j < 4; j++) GLL(pB0 + j * 16, Bcur + j * 4096 + wave * 512);
  asm volatile("s_waitcnt vmcnt(0) lgkmcnt(0)" ::: "memory");
  __builtin_amdgcn_s_barrier();
  READ_FRAGS(Acur, Bcur);

  unsigned ca = 0, pa = 0;  // xn dword for tiles t+1 / t+2

  // ---- relu region: t = 0..6 (A via GLL) ----
  for (int t = 0; t < 7; ++t) {
    const int kt1 = (t + 1) * 64;
#pragma unroll
    for (int j = 0; j < 2; j++)
      GLL(pA0 + j * 32 + kt1, Anxt + j * 4096 + wave * 512);
#pragma unroll
    for (int j = 0; j < 4; j++)
      GLL(pB0 + j * 16 + kt1, Bnxt + j * 4096 + wave * 512);
    if (t == 6) pa = *(const unsigned*)gX;  // xn(tile 8), d0 = 0
    MFMA_ALL();
    asm volatile("s_waitcnt vmcnt(0) lgkmcnt(0)" ::: "memory");
    __builtin_amdgcn_s_barrier();
    READ_FRAGS(Anxt, Bnxt);
    short* tA = Acur; Acur = Anxt; Anxt = tA;
    short* tB = Bcur; Bcur = Bnxt; Bnxt = tB;
    ca = pa;
  }

  // ---- transition t = 7: first basis staging ----
  {
#pragma unroll
    for (int j = 0; j < 4; j++)
      GLL(pB0 + j * 16 + 8 * 64, Bnxt + j * 4096 + wave * 512);
    pa = *(const unsigned*)(gX + 8);  // xn(tile 9)
    basis_write(h2f((unsigned short)(ca & 0xffffu)), LUT, Anxt + bas0);
    basis_write(h2f((unsigned short)(ca >> 16)),     LUT, Anxt + bas0 + 1024);
    MFMA_ALL();
    asm volatile("s_waitcnt vmcnt(0) lgkmcnt(0)" ::: "memory");
    __builtin_amdgcn_s_barrier();
    READ_FRAGS(Anxt, Bnxt);
    short* tA = Acur; Acur = Anxt; Anxt = tA;
    short* tB = Bcur; Bcur = Bnxt; Bnxt = tB;
    ca = pa;
  }

  // ---- steady loop: t = 8..NT-2, ONE branch-free BB, no sched fences ----
  for (int t = 8; t < NT - 1; ++t) {
    const int kt1 = (t + 1) * 64;
#pragma unroll
    for (int j = 0; j < 4; j++)
      GLL(pB0 + j * 16 + kt1, Bnxt + j * 4096 + wave * 512);
    // xn(t+2), address clamped (t=NT-2 re-reads last tile; never consumed)
    const int dd = (t - 6 < 63 ? t - 6 : 63) * 8;
    pa = *(const unsigned*)(gX + dd);
    // basis A(t+1) -> Anxt (independent of MFMA below -> scheduler mixes)
    basis_write(h2f((unsigned short)(ca & 0xffffu)), LUT, Anxt + bas0);
    basis_write(h2f((unsigned short)(ca >> 16)),     LUT, Anxt + bas0 + 1024);
    MFMA_ALL();
    // drain B(t+1) GLLs + publish ds_writes; keep the 2-deep xn prefetch
    asm volatile("s_waitcnt vmcnt(2) lgkmcnt(0)" ::: "memory");
    __builtin_amdgcn_s_barrier();
    READ_FRAGS(Anxt, Bnxt);
    short* tA = Acur; Acur = Anxt; Anxt = tA;
    short* tB = Bcur; Bcur = Bnxt; Bnxt = tB;
    ca = pa;
  }

  // ---- final tile ----
  MFMA_ALL();
#undef READ_FRAGS
#undef MFMA_ALL

  // C/D layout (m89-verified): col = lane&15, row = (lane>>4)*4 + reg
#pragma unroll
  for (int mi = 0; mi < 4; mi++) {
#pragma unroll
    for (int nj = 0; nj < 4; nj++) {
      const int gcol = n0 + wn * 64 + nj * 16 + lr;
#pragma unroll
      for (int r = 0; r < 4; r++) {
        const int grow = m0 + wm * 64 + mi * 16 + q * 4 + r;
        out[(size_t)grow * D_OUT + gcol] = acc[mi][nj][r];
      }
    }
  }
}

extern "C" void kernel_launch(void* const* d_in, const int* in_sizes, int n_in,
                              void* d_out, int out_size, void* d_ws, size_t ws_size,
                              hipStream_t stream) {
  const float* x     = (const float*)d_in[0];
  const float* gamma = (const float*)d_in[1];
  const float* beta  = (const float*)d_in[2];
  const float* bw    = (const float*)d_in[3];
  const float* sw    = (const float*)d_in[4];
  float* out = (float*)d_out;

  short* W  = (short*)d_ws;                          // 512 * 4608 f16
  short* XN = W + (size_t)D_OUT * KTOT;              // 16384 * 512 f16
  short* A0 = XN + (size_t)ROWS * D_IN;              // 16384 * 512 f16

  prep_kernel<<<ROWS / 4 + D_OUT, 256, 0, stream>>>(x, gamma, beta, bw, sw,
                                                    XN, A0, W);
  gemm_kernel<<<256, 512, 0, stream>>>(A0, XN, W, out);
}

// Round 7
// 205.031 us; speedup vs baseline: 1.2757x; 1.2757x over previous
//
#include <hip/hip_runtime.h>
#include <stdint.h>
#include <math.h>

// BSRBF-KAN layer, SPLIT pipeline (round 7):
// out = relu(LN(x)) @ base_W^T + (bspline+rbf)(LN(x)) @ spline_W^T
// Round-7 rationale: rounds 2-6 showed every FUSED schedule is bound by a
// serial LDS budget (~176 KB/tile/CU) that no barrier structure overlapped;
// fused gemm never beat 120 us.  Split components have measured floors:
//  * gemm: round-0 structure VERBATIM (128x128 tile, 4 waves, XOR bank
//    swizzle, global_load_lds w16, 2 blocks/CU, grid 512) = 92 us measured.
//    Only delta: f16 MFMA (f16 datapath verified rounds 3-6).
//  * prep: wprep + LN + relu + basis materialization, with the round-3
//    verified cheap eval (perm-LUT spline select + 3-transcendental RBF
//    cascade, ~55 VALU/eval vs round-0's ~190).  Basis stores are
//    coalesced 1KB/wave (lane owns d = e*64+lane).  Floor: 180 MB -> ~30 us.
//   ws: [W: 512*4608 f16][A: 16384*4608 f16]

#define D_IN  512
#define D_OUT 512
#define NB    8
#define KTOT  (D_IN + D_IN * NB)   // 4608
#define ROWS  16384

typedef __attribute__((ext_vector_type(2))) _Float16 f16x2;
typedef __attribute__((ext_vector_type(8))) _Float16 f16x8;
typedef __attribute__((ext_vector_type(4))) float f32x4;

__device__ __forceinline__ short f2h(float f) {
  return (short)__builtin_bit_cast(unsigned short, (_Float16)f);  // RNE
}
__device__ __forceinline__ unsigned pkrtz_u(float a, float b) {
  return __builtin_bit_cast(unsigned, __builtin_amdgcn_cvt_pkrtz(a, b));
}
__device__ __forceinline__ unsigned pkadd_f16(unsigned a, unsigned b) {
  f16x2 x = __builtin_bit_cast(f16x2, a), y = __builtin_bit_cast(f16x2, b);
  f16x2 r = x + y;
  return __builtin_bit_cast(unsigned, r);
}

// ---------------- basis eval: one d -> 8 packed f16 (spline + rbf) -------
// (verified rounds 3-6) Spline: closed-form uniform cubic, knots
// (i-3)*0.6 - 1.5; selection via 14-entry perm-selector LUT.
// RBF cascade: z = (xn+1.5)*(7/3)*sqrt(log2 e); R_j = exp2(-(z-j*DLT)^2),
// DLT^2 = log2 e  =>  R_{j+1} = R_j * G * e^-(2j+1), G = exp2(2*DLT*z);
// anchor j=3; z clamped to [-8,16] (no inf*0, tails underflow to 0).
__device__ __forceinline__ void basis_write(float xn, const uint4* lut,
                                            short* dst) {
  const float u = fmaf(xn, 1.66666667f, 5.5f);  // (xn+3.3)/0.6
  const float cf = floorf(u);
  const int c = (int)cf;
  const float t = u - cf;
  const float t2 = t * t, t3 = t2 * t, omt = 1.0f - t;
  const float v0 = t3 * 0.16666667f;
  const float v1 = fmaf(fmaf(fmaf(t, -0.5f, 0.5f), t, 0.5f), t, 0.16666667f);
  const float v2 = fmaf(t3, 0.5f, fmaf(t2, -1.0f, 0.66666667f));
  const float v3 = omt * omt * (omt * 0.16666667f);
  const unsigned va = pkrtz_u(v0, v1);
  const unsigned vb = pkrtz_u(v2, v3);

  float z = fmaf(xn, 2.80261895f, 4.20392842f);
  z = fminf(fmaxf(z, -8.0f), 16.0f);
  const float d3 = z - 3.60336723f;              // 3*DLT
  const float R3 = __builtin_amdgcn_exp2f(-(d3 * d3));
  const float G  = __builtin_amdgcn_exp2f(z * 2.40224482f);  // 2*DLT
  const float Gi = __builtin_amdgcn_rcpf(G);
  const float R4 = R3 * (G * 9.11881966e-4f);    // e^-7
  const float R5 = R4 * (G * 1.23409804e-4f);    // e^-9
  const float R6 = R5 * (G * 1.67017007e-5f);    // e^-11
  const float R7 = R6 * (G * 2.26032941e-6f);    // e^-13
  const float R2 = R3 * (Gi * 148.413159f);      // e^5
  const float R1 = R2 * (Gi * 20.0855369f);      // e^3
  const float R0 = R1 * (Gi * 2.71828183f);      // e^1

  const int idx = (c < -1 ? -1 : (c > 12 ? 12 : c)) + 1;
  const uint4 sel = lut[idx];
  const unsigned w0 = pkadd_f16(__builtin_amdgcn_perm(vb, va, sel.x), pkrtz_u(R0, R1));
  const unsigned w1 = pkadd_f16(__builtin_amdgcn_perm(vb, va, sel.y), pkrtz_u(R2, R3));
  const unsigned w2 = pkadd_f16(__builtin_amdgcn_perm(vb, va, sel.z), pkrtz_u(R4, R5));
  const unsigned w3 = pkadd_f16(__builtin_amdgcn_perm(vb, va, sel.w), pkrtz_u(R6, R7));
  const uint4 v4 = {w0, w1, w2, w3};
  *(uint4*)dst = v4;  // 16B store (coalesced 1KB/wave across lanes)
}

// ---------------- prep: wprep + LN + relu + basis -> A[ROWS][KTOT] -------
__global__ __launch_bounds__(256) void prep_kernel(
    const float* __restrict__ x, const float* __restrict__ gamma,
    const float* __restrict__ beta, const float* __restrict__ bw,
    const float* __restrict__ sw, short* __restrict__ A,
    short* __restrict__ W) {
  if (blockIdx.x >= ROWS / 4) {
    // ---- weight prep: interleave + fp32->f16, one block per out-row ----
    const int o = blockIdx.x - ROWS / 4;
    for (int k = threadIdx.x; k < KTOT; k += 256) {
      const float v = (k < D_IN) ? bw[o * D_IN + k]
                                 : sw[(size_t)o * (D_IN * NB) + (k - D_IN)];
      W[(size_t)o * KTOT + k] = f2h(v);
    }
    return;
  }
  __shared__ uint4 LUT[14];
  const int tid = threadIdx.x;
  if (tid < 14) {  // perm-selector LUT: entry idx = c+1, c clamped [-1,12]
    const int cc = tid - 1;
    unsigned e[4];
#pragma unroll
    for (int h = 0; h < 4; ++h) {
      const int m = cc - 2 * h, m2 = m - 1;
      const unsigned lo =
          (m >= 0 && m <= 3) ? (unsigned)((2 * m) | ((2 * m + 1) << 8)) : 0x0C0Cu;
      const unsigned hi =
          (m2 >= 0 && m2 <= 3) ? (unsigned)((2 * m2) | ((2 * m2 + 1) << 8)) : 0x0C0Cu;
      e[h] = lo | (hi << 16);
    }
    const uint4 ev = {e[0], e[1], e[2], e[3]};
    LUT[tid] = ev;
  }
  __syncthreads();

  // ---- LN + relu + basis; one wave per row, lane owns d = e*64+lane ----
  const int lane = tid & 63, wave = tid >> 6;
  const int row = blockIdx.x * 4 + wave;
  const float* xr = x + (size_t)row * D_IN;

  float xv[8];
  float s = 0.0f, ss = 0.0f;
#pragma unroll
  for (int e = 0; e < 8; e++) {
    xv[e] = xr[e * 64 + lane];
    s += xv[e];
    ss += xv[e] * xv[e];
  }
#pragma unroll
  for (int off = 32; off > 0; off >>= 1) {
    s += __shfl_xor(s, off);
    ss += __shfl_xor(ss, off);
  }
  const float mu = s * (1.0f / D_IN);
  const float var = ss * (1.0f / D_IN) - mu * mu;
  const float rstd = 1.0f / sqrtf(var + 1e-5f);

  short* Ar = A + (size_t)row * KTOT;
#pragma unroll
  for (int e = 0; e < 8; e++) {
    const int d = e * 64 + lane;
    const float xn = fmaf((xv[e] - mu) * rstd, gamma[d], beta[d]);
    Ar[d] = f2h(fmaxf(xn, 0.0f));                    // relu region (2B, coalesced)
    basis_write(xn, LUT, &Ar[D_IN + d * NB]);        // basis region (16B, coalesced)
  }
}

// ---------------- f16 MFMA GEMM: C[M,N] = A[M,K] * W[N,K]^T --------------
// Round-0 structure VERBATIM (measured 92 us / 838 TF / 0 conflicts):
// LDS slot (r, c) holds global chunk  c ^ (r & 7)  -> zero bank conflicts.
// 128x128 tile, BK=64, 4 waves, global_load_lds width 16, 2 blocks/CU,
// n-minor block order (blocks 4g..4g+3 share one A m-tile through L3).
#define GLL(g, l)                                               \
  __builtin_amdgcn_global_load_lds(                             \
      (const __attribute__((address_space(1))) void*)(g),       \
      (__attribute__((address_space(3))) void*)(l), 16, 0, 0)

__global__ __launch_bounds__(256, 2) void gemm_kernel(
    const short* __restrict__ A, const short* __restrict__ W,
    float* __restrict__ out) {
  __shared__ short As[128 * 64];  // 16 KB
  __shared__ short Bs[128 * 64];  // 16 KB
  const int tid = threadIdx.x;
  const int lane = tid & 63, wave = tid >> 6;

  const int f = blockIdx.x;
  const int m0 = (f >> 2) * 128;
  const int n0 = (f & 3) * 128;
  const int wm = wave & 1, wn = wave >> 1;

  const f32x4 zero = {0.0f, 0.0f, 0.0f, 0.0f};
  f32x4 acc[4][4];
#pragma unroll
  for (int i = 0; i < 4; i++)
#pragma unroll
    for (int j = 0; j < 4; j++) acc[i][j] = zero;

  // staging: thread -> (row r0 = tid>>3 in 0..31, chunk-slot c0 = tid&7);
  // 4 rounds add +32 rows. Source global chunk = c0 ^ (r0 & 7).
  const int r0 = tid >> 3;
  const int c0 = tid & 7;
  const int qsrc = c0 ^ (r0 & 7);
  const short* gA = A + (size_t)(m0 + r0) * KTOT + qsrc * 8;
  const short* gB = W + (size_t)(n0 + r0) * KTOT + qsrc * 8;
  short* lA = As + wave * 512;  // wave-uniform base; HW scatters lane*16B
  short* lB = Bs + wave * 512;

  const int lr = lane & 15;
  const int q = lane >> 4;
  const int x7 = lr & 7;

  for (int kt = 0; kt < KTOT; kt += 64) {
    __syncthreads();
#pragma unroll
    for (int rd = 0; rd < 4; rd++) {
      GLL(gA + (size_t)(32 * rd) * KTOT + kt, lA + rd * 2048);
      GLL(gB + (size_t)(32 * rd) * KTOT + kt, lB + rd * 2048);
    }
    __syncthreads();
#pragma unroll
    for (int kk2 = 0; kk2 < 2; kk2++) {
      const int gq = kk2 * 4 + q;   // global chunk this lane consumes
      f16x8 af[4], bf[4];
#pragma unroll
      for (int mi = 0; mi < 4; mi++)
        af[mi] = *(const f16x8*)&As[(wm * 64 + mi * 16 + lr) * 64 + ((gq ^ x7) * 8)];
#pragma unroll
      for (int nj = 0; nj < 4; nj++)
        bf[nj] = *(const f16x8*)&Bs[(wn * 64 + nj * 16 + lr) * 64 + ((gq ^ x7) * 8)];
#pragma unroll
      for (int mi = 0; mi < 4; mi++)
#pragma unroll
        for (int nj = 0; nj < 4; nj++)
          acc[mi][nj] = __builtin_amdgcn_mfma_f32_16x16x32_f16(
              af[mi], bf[nj], acc[mi][nj], 0, 0, 0);
    }
  }

  // C/D layout (m89-verified): col = lane&15, row = (lane>>4)*4 + reg
#pragma unroll
  for (int mi = 0; mi < 4; mi++) {
#pragma unroll
    for (int nj = 0; nj < 4; nj++) {
      const int gcol = n0 + wn * 64 + nj * 16 + lr;
#pragma unroll
      for (int r = 0; r < 4; r++) {
        const int grow = m0 + wm * 64 + mi * 16 + q * 4 + r;
        out[(size_t)grow * D_OUT + gcol] = acc[mi][nj][r];
      }
    }
  }
}

extern "C" void kernel_launch(void* const* d_in, const int* in_sizes, int n_in,
                              void* d_out, int out_size, void* d_ws, size_t ws_size,
                              hipStream_t stream) {
  const float* x     = (const float*)d_in[0];
  const float* gamma = (const float*)d_in[1];
  const float* beta  = (const float*)d_in[2];
  const float* bw    = (const float*)d_in[3];
  const float* sw    = (const float*)d_in[4];
  float* out = (float*)d_out;

  short* W = (short*)d_ws;                         // 512 * 4608 f16
  short* A = (short*)d_ws + (size_t)D_OUT * KTOT;  // 16384 * 4608 f16

  prep_kernel<<<ROWS / 4 + D_OUT, 256, 0, stream>>>(x, gamma, beta, bw, sw, A, W);
  gemm_kernel<<<512, 256, 0, stream>>>(A, W, out);
}

// Round 9
// 184.066 us; speedup vs baseline: 1.4210x; 1.1139x over previous
//
#include <hip/hip_runtime.h>
#include <stdint.h>
#include <math.h>

// BSRBF-KAN layer, SPLIT pipeline (round 9 = round 8 resubmit; r8 bench was
// a container-level infra failure with no pytest/timing output):
// out = relu(LN(x)) @ base_W^T + (bspline+rbf)(LN(x)) @ spline_W^T
//  * prep: unchanged from round 7 (wprep + LN + relu + basis -> A f16).
//  * gemm: counted-vmcnt deep pipeline (T3+T4): BM=256 x BN=128, BK=64,
//    8 waves, TRIPLE-buffered A+B (144 KB LDS, 1 block/CU).  One s_barrier
//    per K-tile; steady-state wait vmcnt(6): tile t+2's 6 global_load_lds
//    stay in flight across the barrier, tile t+1's (oldest 6) drain.
//    Race audit (r9): per-wave vmcnt wait precedes the shared barrier ->
//    all waves' t+1 GLLs complete before any wave reads them; buffer
//    re-written at iter t was last read at t-1 and those reads are consumed
//    by MFMAs before barrier(t-1).  LDS layout = R7's verified XOR swizzle
//    (slot (r,c) holds chunk c^(r&7); coalesced GLL source, 0 conflicts).
//    XCD-chunked remap wg=(b&7)*32+(b>>3): each A m-panel's 4 n-blocks
//    land on one XCD -> A fetched ~once from HBM (FETCH 300 -> ~190 MB).
//   ws: [W: 512*4608 f16][A: 16384*4608 f16]

#define D_IN  512
#define D_OUT 512
#define NB    8
#define KTOT  (D_IN + D_IN * NB)   // 4608
#define ROWS  16384
#define NT    (KTOT / 64)          // 72

typedef __attribute__((ext_vector_type(2))) _Float16 f16x2;
typedef __attribute__((ext_vector_type(8))) _Float16 f16x8;
typedef __attribute__((ext_vector_type(4))) float f32x4;

__device__ __forceinline__ short f2h(float f) {
  return (short)__builtin_bit_cast(unsigned short, (_Float16)f);  // RNE
}
__device__ __forceinline__ unsigned pkrtz_u(float a, float b) {
  return __builtin_bit_cast(unsigned, __builtin_amdgcn_cvt_pkrtz(a, b));
}
__device__ __forceinline__ unsigned pkadd_f16(unsigned a, unsigned b) {
  f16x2 x = __builtin_bit_cast(f16x2, a), y = __builtin_bit_cast(f16x2, b);
  f16x2 r = x + y;
  return __builtin_bit_cast(unsigned, r);
}

// ---------------- basis eval: one d -> 8 packed f16 (spline + rbf) -------
// (verified rounds 3-7) Spline: closed-form uniform cubic, knots
// (i-3)*0.6 - 1.5; selection via 14-entry perm-selector LUT.
// RBF cascade: 3 transcendentals; z clamped to [-8,16].
__device__ __forceinline__ void basis_write(float xn, const uint4* lut,
                                            short* dst) {
  const float u = fmaf(xn, 1.66666667f, 5.5f);  // (xn+3.3)/0.6
  const float cf = floorf(u);
  const int c = (int)cf;
  const float t = u - cf;
  const float t2 = t * t, t3 = t2 * t, omt = 1.0f - t;
  const float v0 = t3 * 0.16666667f;
  const float v1 = fmaf(fmaf(fmaf(t, -0.5f, 0.5f), t, 0.5f), t, 0.16666667f);
  const float v2 = fmaf(t3, 0.5f, fmaf(t2, -1.0f, 0.66666667f));
  const float v3 = omt * omt * (omt * 0.16666667f);
  const unsigned va = pkrtz_u(v0, v1);
  const unsigned vb = pkrtz_u(v2, v3);

  float z = fmaf(xn, 2.80261895f, 4.20392842f);
  z = fminf(fmaxf(z, -8.0f), 16.0f);
  const float d3 = z - 3.60336723f;              // 3*DLT
  const float R3 = __builtin_amdgcn_exp2f(-(d3 * d3));
  const float G  = __builtin_amdgcn_exp2f(z * 2.40224482f);  // 2*DLT
  const float Gi = __builtin_amdgcn_rcpf(G);
  const float R4 = R3 * (G * 9.11881966e-4f);    // e^-7
  const float R5 = R4 * (G * 1.23409804e-4f);    // e^-9
  const float R6 = R5 * (G * 1.67017007e-5f);    // e^-11
  const float R7 = R6 * (G * 2.26032941e-6f);    // e^-13
  const float R2 = R3 * (Gi * 148.413159f);      // e^5
  const float R1 = R2 * (Gi * 20.0855369f);      // e^3
  const float R0 = R1 * (Gi * 2.71828183f);      // e^1

  const int idx = (c < -1 ? -1 : (c > 12 ? 12 : c)) + 1;
  const uint4 sel = lut[idx];
  const unsigned w0 = pkadd_f16(__builtin_amdgcn_perm(vb, va, sel.x), pkrtz_u(R0, R1));
  const unsigned w1 = pkadd_f16(__builtin_amdgcn_perm(vb, va, sel.y), pkrtz_u(R2, R3));
  const unsigned w2 = pkadd_f16(__builtin_amdgcn_perm(vb, va, sel.z), pkrtz_u(R4, R5));
  const unsigned w3 = pkadd_f16(__builtin_amdgcn_perm(vb, va, sel.w), pkrtz_u(R6, R7));
  const uint4 v4 = {w0, w1, w2, w3};
  *(uint4*)dst = v4;  // 16B store (coalesced 1KB/wave across lanes)
}

// ---------------- prep: wprep + LN + relu + basis -> A[ROWS][KTOT] -------
__global__ __launch_bounds__(256) void prep_kernel(
    const float* __restrict__ x, const float* __restrict__ gamma,
    const float* __restrict__ beta, const float* __restrict__ bw,
    const float* __restrict__ sw, short* __restrict__ A,
    short* __restrict__ W) {
  if (blockIdx.x >= ROWS / 4) {
    const int o = blockIdx.x - ROWS / 4;
    for (int k = threadIdx.x; k < KTOT; k += 256) {
      const float v = (k < D_IN) ? bw[o * D_IN + k]
                                 : sw[(size_t)o * (D_IN * NB) + (k - D_IN)];
      W[(size_t)o * KTOT + k] = f2h(v);
    }
    return;
  }
  __shared__ uint4 LUT[14];
  const int tid = threadIdx.x;
  if (tid < 14) {
    const int cc = tid - 1;
    unsigned e[4];
#pragma unroll
    for (int h = 0; h < 4; ++h) {
      const int m = cc - 2 * h, m2 = m - 1;
      const unsigned lo =
          (m >= 0 && m <= 3) ? (unsigned)((2 * m) | ((2 * m + 1) << 8)) : 0x0C0Cu;
      const unsigned hi =
          (m2 >= 0 && m2 <= 3) ? (unsigned)((2 * m2) | ((2 * m2 + 1) << 8)) : 0x0C0Cu;
      e[h] = lo | (hi << 16);
    }
    const uint4 ev = {e[0], e[1], e[2], e[3]};
    LUT[tid] = ev;
  }
  __syncthreads();

  const int lane = tid & 63, wave = tid >> 6;
  const int row = blockIdx.x * 4 + wave;
  const float* xr = x + (size_t)row * D_IN;

  float xv[8];
  float s = 0.0f, ss = 0.0f;
#pragma unroll
  for (int e = 0; e < 8; e++) {
    xv[e] = xr[e * 64 + lane];
    s += xv[e];
    ss += xv[e] * xv[e];
  }
#pragma unroll
  for (int off = 32; off > 0; off >>= 1) {
    s += __shfl_xor(s, off);
    ss += __shfl_xor(ss, off);
  }
  const float mu = s * (1.0f / D_IN);
  const float var = ss * (1.0f / D_IN) - mu * mu;
  const float rstd = 1.0f / sqrtf(var + 1e-5f);

  short* Ar = A + (size_t)row * KTOT;
#pragma unroll
  for (int e = 0; e < 8; e++) {
    const int d = e * 64 + lane;
    const float xn = fmaf((xv[e] - mu) * rstd, gamma[d], beta[d]);
    Ar[d] = f2h(fmaxf(xn, 0.0f));
    basis_write(xn, LUT, &Ar[D_IN + d * NB]);
  }
}

// ---------------- f16 MFMA GEMM: counted-vmcnt triple-buffer pipeline ----
#define GLL(g, l)                                               \
  __builtin_amdgcn_global_load_lds(                             \
      (const __attribute__((address_space(1))) void*)(g),       \
      (__attribute__((address_space(3))) void*)(l), 16, 0, 0)

__global__ __launch_bounds__(512, 1) void gemm_kernel(
    const short* __restrict__ A, const short* __restrict__ W,
    float* __restrict__ out) {
  __shared__ short Ab[3 * 256 * 64];  // 96 KB, A triple-buffer
  __shared__ short Bb[3 * 128 * 64];  // 48 KB, B triple-buffer
  const int tid = threadIdx.x;                 // 512
  const int lane = tid & 63, wave = tid >> 6;  // 8 waves

  // XCD-chunked remap (bijective, 256 = 8*32): XCD x runs wg in [32x, 32x+32)
  // = m-panels 8x..8x+7, each with its 4 n-blocks -> A panel read by ONE XCD.
  const int b = blockIdx.x;
  const int wg = (b & 7) * 32 + (b >> 3);
  const int m0 = (wg >> 2) * 256;
  const int n0 = (wg & 3) * 128;
  const int wm = wave >> 1, wn = wave & 1;  // per-wave 64x64 output

  const f32x4 zero = {0.0f, 0.0f, 0.0f, 0.0f};
  f32x4 acc[4][4];
#pragma unroll
  for (int i = 0; i < 4; i++)
#pragma unroll
    for (int j = 0; j < 4; j++) acc[i][j] = zero;

  // staging map (R7-verified): thread -> (row r0 = tid>>3 in 0..63,
  // chunk-slot c0 = tid&7); calls add +64 rows; src chunk = c0 ^ (r0&7).
  // Coalesced: 8 threads/row read 8 consecutive 16B chunks (128B segments).
  const int r0 = tid >> 3;
  const int c0 = tid & 7;
  const int qsrc = c0 ^ (r0 & 7);
  const short* gA = A + (size_t)(m0 + r0) * KTOT + qsrc * 8;
  const short* gB = W + (size_t)(n0 + r0) * KTOT + qsrc * 8;
  const int lbase = wave * 512;  // wave-uniform dest base; HW adds lane*16B

  const int lr = lane & 15;
  const int q = lane >> 4;
  const int x7 = lr & 7;

  short* A0p = Ab;  short* A1p = Ab + 16384;  short* A2p = Ab + 32768;
  short* B0p = Bb;  short* B1p = Bb + 8192;   short* B2p = Bb + 16384;

  // 6 GLLs per tile: A rows 0..255 (4 calls), B rows 0..127 (2 calls)
#define STAGE_A01(Ad, Bd, kt)                                          \
  do {                                                                 \
    GLL(gA + (kt), (Ad) + lbase);                                      \
    GLL(gA + (size_t)64 * KTOT + (kt), (Ad) + 4096 + lbase);           \
    GLL(gB + (kt), (Bd) + lbase);                                      \
  } while (0)
#define STAGE_A23(Ad, Bd, kt)                                          \
  do {                                                                 \
    GLL(gA + (size_t)128 * KTOT + (kt), (Ad) + 8192 + lbase);          \
    GLL(gA + (size_t)192 * KTOT + (kt), (Ad) + 12288 + lbase);         \
    GLL(gB + (size_t)64 * KTOT + (kt), (Bd) + 4096 + lbase);           \
  } while (0)

  f16x8 af[2][4], bf[2][4];
#define READ_K(kk2, Ac, Bc)                                                    \
  do {                                                                         \
    const int off = (((kk2) * 4 + q) ^ x7) * 8;                                \
    _Pragma("unroll")                                                          \
    for (int mi = 0; mi < 4; mi++)                                             \
      af[kk2][mi] = *(const f16x8*)&(Ac)[(wm * 64 + mi * 16 + lr) * 64 + off]; \
    _Pragma("unroll")                                                          \
    for (int nj = 0; nj < 4; nj++)                                             \
      bf[kk2][nj] = *(const f16x8*)&(Bc)[(wn * 64 + nj * 16 + lr) * 64 + off]; \
  } while (0)

#define MFMA_K(kk2)                                                            \
  do {                                                                         \
    __builtin_amdgcn_s_setprio(1);                                             \
    _Pragma("unroll")                                                          \
    for (int mi = 0; mi < 4; mi++)                                             \
      _Pragma("unroll")                                                        \
      for (int nj = 0; nj < 4; nj++)                                           \
        acc[mi][nj] = __builtin_amdgcn_mfma_f32_16x16x32_f16(                  \
            af[kk2][mi], bf[kk2][nj], acc[mi][nj], 0, 0, 0);                   \
    __builtin_amdgcn_s_setprio(0);                                             \
  } while (0)

  // prologue: stage tiles 0 and 1; wait tile 0 (keep tile 1's 6 in flight)
  STAGE_A01(A0p, B0p, 0);
  STAGE_A23(A0p, B0p, 0);
  STAGE_A01(A1p, B1p, 64);
  STAGE_A23(A1p, B1p, 64);
  __builtin_amdgcn_sched_barrier(0);
  asm volatile("s_waitcnt vmcnt(6)" ::: "memory");
  __builtin_amdgcn_s_barrier();
  __builtin_amdgcn_sched_barrier(0);

  short* cA = A0p; short* nA = A1p; short* sA = A2p;
  short* cB = B0p; short* nB = B1p; short* sB = B2p;

  // steady loop: compute tile t, stage tile t+2, one barrier per tile.
  // End-of-tile wait vmcnt(6): drains t+1's 6 (oldest), keeps t+2's 6.
  for (int t = 0; t < NT - 2; ++t) {
    const int kt2 = (t + 2) * 64;
    READ_K(0, cA, cB);
    STAGE_A01(sA, sB, kt2);
    MFMA_K(0);
    READ_K(1, cA, cB);
    STAGE_A23(sA, sB, kt2);
    MFMA_K(1);
    __builtin_amdgcn_sched_barrier(0);
    asm volatile("s_waitcnt vmcnt(6)" ::: "memory");
    __builtin_amdgcn_s_barrier();
    __builtin_amdgcn_sched_barrier(0);
    short* tp;
    tp = cA; cA = nA; nA = sA; sA = tp;
    tp = cB; cB = nB; nB = sB; sB = tp;
  }

  // t = NT-2: no staging; drain tile NT-1's loads fully
  READ_K(0, cA, cB);
  MFMA_K(0);
  READ_K(1, cA, cB);
  MFMA_K(1);
  __builtin_amdgcn_sched_barrier(0);
  asm volatile("s_waitcnt vmcnt(0)" ::: "memory");
  __builtin_amdgcn_s_barrier();
  __builtin_amdgcn_sched_barrier(0);
  cA = nA; cB = nB;

  // t = NT-1: final tile
  READ_K(0, cA, cB);
  MFMA_K(0);
  READ_K(1, cA, cB);
  MFMA_K(1);

#undef READ_K
#undef MFMA_K
#undef STAGE_A01
#undef STAGE_A23

  // C/D layout (m89-verified): col = lane&15, row = (lane>>4)*4 + reg
#pragma unroll
  for (int mi = 0; mi < 4; mi++) {
#pragma unroll
    for (int nj = 0; nj < 4; nj++) {
      const int gcol = n0 + wn * 64 + nj * 16 + lr;
#pragma unroll
      for (int r = 0; r < 4; r++) {
        const int grow = m0 + wm * 64 + mi * 16 + q * 4 + r;
        out[(size_t)grow * D_OUT + gcol] = acc[mi][nj][r];
      }
    }
  }
}

extern "C" void kernel_launch(void* const* d_in, const int* in_sizes, int n_in,
                              void* d_out, int out_size, void* d_ws, size_t ws_size,
                              hipStream_t stream) {
  const float* x     = (const float*)d_in[0];
  const float* gamma = (const float*)d_in[1];
  const float* beta  = (const float*)d_in[2];
  const float* bw    = (const float*)d_in[3];
  const float* sw    = (const float*)d_in[4];
  float* out = (float*)d_out;

  short* W = (short*)d_ws;                         // 512 * 4608 f16
  short* A = (short*)d_ws + (size_t)D_OUT * KTOT;  // 16384 * 4608 f16

  prep_kernel<<<ROWS / 4 + D_OUT, 256, 0, stream>>>(x, gamma, beta, bw, sw, A, W);
  gemm_kernel<<<256, 512, 0, stream>>>(A, W, out);
}